// Round 1
// baseline (229.252 us; speedup 1.0000x reference)
//
#include <hip/hip_runtime.h>

// SparseAttention: x[8,8192,256] -> QKV proj (+ per-head P proj folded into
// weights) -> block-diagonal (BS=8) softmax attention -> out[8,8192,256] fp32.
//
// Kernel 1 (prep_weights): W_effT[768][256] bf16, c = [Q(0..255)|K(256..511)|V(512..767)]
//   Q/K cols have P folded in:  W_effT[h*128+i][e] = sum_d Wq[h*128+d][e] * P[d][i]
//   V cols are just Wv transposed. bias_eff likewise (zeros in practice).
// Kernel 2 (fused): per 32-token tile: stage x->bf16 LDS, MFMA GEMM vs W_effT
//   (L2-resident), QKV -> swizzled LDS, per-(8-block, head) attention per wave.

typedef __attribute__((ext_vector_type(8))) short bf16x8;
typedef __attribute__((ext_vector_type(4))) float f32x4;

__device__ __forceinline__ short f2bf(float f) {
  unsigned int u = __builtin_bit_cast(unsigned int, f);
  u = (u + 0x7FFFu + ((u >> 16) & 1u)) >> 16;  // RNE
  return (short)u;
}
__device__ __forceinline__ float bf2f(short s) {
  unsigned int u = ((unsigned int)(unsigned short)s) << 16;
  return __builtin_bit_cast(float, u);
}
// LDS XOR swizzle: distinct 16B slots for rows that would otherwise alias banks
__device__ __forceinline__ int swz(int r) { return ((r ^ (r >> 3)) & 7) << 4; }

__global__ void prep_weights(const float* __restrict__ Wq, const float* __restrict__ bq,
                             const float* __restrict__ Wk, const float* __restrict__ bk,
                             const float* __restrict__ Wv, const float* __restrict__ bv,
                             const float* __restrict__ P,
                             short* __restrict__ WT, float* __restrict__ beff) {
  const int c = blockIdx.x;   // 0..767 output column
  const int e = threadIdx.x;  // 0..255 input dim
  float acc = 0.f, bacc = 0.f;
  if (c < 512) {
    const float* W  = (c < 256) ? Wq : Wk;
    const float* bb = (c < 256) ? bq : bk;
    const int cc = c & 255;
    const int h = cc >> 7, i = cc & 127;
    for (int d = 0; d < 128; ++d) {
      const float p = P[d * 128 + i];
      acc += W[(h * 128 + d) * 256 + e] * p;   // coalesced over e
      if (e == 0) bacc += bb[h * 128 + d] * p;
    }
  } else {
    const int cc = c - 512;
    acc = Wv[cc * 256 + e];
    bacc = bv[cc];
  }
  WT[c * 256 + e] = f2bf(acc);
  if (e == 0) beff[c] = bacc;
}

__global__ __launch_bounds__(512, 4)
void fused_qkv_attn(const float* __restrict__ x, const short* __restrict__ WT,
                    const float* __restrict__ beff, float* __restrict__ out) {
  // LDS: xa = x tile [32 rows][512 B] (bf16, swizzled)
  //      qk = QKV tile [32 rows][1536 B] (bf16, swizzled); cols 0..255 Q, 256..511 K, 512..767 V
  __shared__ __align__(16) char lds[65536];
  char* const xa = lds;
  char* const qk = lds + 16384;

  const int tid = threadIdx.x;
  const long tok0 = (long)blockIdx.x * 32;

  // ---- Phase 1: stage x (32x256 fp32) -> bf16 LDS ----
  {
    const int r  = tid >> 4;          // token row 0..31
    const int kc = (tid & 15) * 16;   // element base
    const float4* xp = (const float4*)(x + (tok0 + r) * 256 + kc);
    float4 f0 = xp[0], f1 = xp[1], f2 = xp[2], f3 = xp[3];
    bf16x8 v0, v1;
    v0[0]=f2bf(f0.x); v0[1]=f2bf(f0.y); v0[2]=f2bf(f0.z); v0[3]=f2bf(f0.w);
    v0[4]=f2bf(f1.x); v0[5]=f2bf(f1.y); v0[6]=f2bf(f1.z); v0[7]=f2bf(f1.w);
    v1[0]=f2bf(f2.x); v1[1]=f2bf(f2.y); v1[2]=f2bf(f2.z); v1[3]=f2bf(f2.w);
    v1[4]=f2bf(f3.x); v1[5]=f2bf(f3.y); v1[6]=f2bf(f3.z); v1[7]=f2bf(f3.w);
    *(bf16x8*)(xa + r * 512 + ((kc * 2)       ^ swz(r))) = v0;
    *(bf16x8*)(xa + r * 512 + ((kc * 2 + 16)  ^ swz(r))) = v1;
  }
  __syncthreads();

  const int w = tid >> 6, l = tid & 63;
  const int lrow = l & 15, lk = l >> 4;
  const int nb = w * 96;  // this wave's 96 output cols

  // ---- Phase 2: GEMM (32 x 768 = x_tile @ W_effT^T), acc[mf][nf] ----
  f32x4 acc[2][6];
#pragma unroll
  for (int nf = 0; nf < 6; ++nf) {
    const float bv_ = beff[nb + nf * 16 + lrow];  // bias per output col
    acc[0][nf] = (f32x4){bv_, bv_, bv_, bv_};
    acc[1][nf] = acc[0][nf];
  }
#pragma unroll
  for (int ks = 0; ks < 8; ++ks) {
    const int kb = ks * 32;
    // A frags: A[row][k], row = l&15 (+16), k = kb + (l>>4)*8 + e
    bf16x8 a0 = *(const bf16x8*)(xa + lrow        * 512 + ((kb * 2 + lk * 16) ^ swz(lrow)));
    bf16x8 a1 = *(const bf16x8*)(xa + (16 + lrow) * 512 + ((kb * 2 + lk * 16) ^ swz(16 + lrow)));
#pragma unroll
    for (int nf = 0; nf < 6; ++nf) {
      // B frag: B[k][col], col = l&15; W_effT[col][k..k+8] contiguous 16B (L2-hot)
      const int col = nb + nf * 16 + lrow;
      bf16x8 b = *(const bf16x8*)(WT + col * 256 + kb + lk * 8);
      acc[0][nf] = __builtin_amdgcn_mfma_f32_16x16x32_bf16(a0, b, acc[0][nf], 0, 0, 0);
      acc[1][nf] = __builtin_amdgcn_mfma_f32_16x16x32_bf16(a1, b, acc[1][nf], 0, 0, 0);
    }
  }

  // ---- Phase 3: acc (C[row=(l>>4)*4+r][col=l&15]) -> qkv LDS as bf16 ----
#pragma unroll
  for (int mf = 0; mf < 2; ++mf)
#pragma unroll
    for (int nf = 0; nf < 6; ++nf)
#pragma unroll
      for (int r = 0; r < 4; ++r) {
        const int tok = mf * 16 + lk * 4 + r;
        const int c   = nb + nf * 16 + lrow;
        *(short*)(qk + tok * 1536 + ((c * 2) ^ swz(tok))) = f2bf(acc[mf][nf][r]);
      }
  __syncthreads();

  // ---- Phase 4: block-diagonal attention; one wave = one (8-block, head) ----
  {
    const int blk = w >> 1, h = w & 1;
    const int i = l >> 3, j = l & 7;      // query row, key col
    const int tq = blk * 8 + i, tk = blk * 8 + j;
    const int qc = h * 128, kcc = 256 + h * 128, vcc = 512 + h * 128;
    float s = 0.f;
#pragma unroll
    for (int dc = 0; dc < 16; ++dc) {
      bf16x8 qv = *(const bf16x8*)(qk + tq * 1536 + (((qc  + dc * 8) * 2) ^ swz(tq)));
      bf16x8 kv = *(const bf16x8*)(qk + tk * 1536 + (((kcc + dc * 8) * 2) ^ swz(tk)));
#pragma unroll
      for (int e = 0; e < 8; ++e) s += bf2f(qv[e]) * bf2f(kv[e]);
    }
    s *= 0.08838834764831843f;  // 1/sqrt(128)

    // softmax over the 8 keys (lanes i*8 .. i*8+7)
    float mx = s;
    mx = fmaxf(mx, __shfl_xor(mx, 1, 8));
    mx = fmaxf(mx, __shfl_xor(mx, 2, 8));
    mx = fmaxf(mx, __shfl_xor(mx, 4, 8));
    const float p = __expf(s - mx);
    float sum = p;
    sum += __shfl_xor(sum, 1, 8);
    sum += __shfl_xor(sum, 2, 8);
    sum += __shfl_xor(sum, 4, 8);
    const float pn = p / sum;

    // PV: lane handles (row i, d-chunk j*16 .. +15)
    const int d0 = j * 16;
    float o[16];
#pragma unroll
    for (int c = 0; c < 16; ++c) o[c] = 0.f;
#pragma unroll
    for (int jj = 0; jj < 8; ++jj) {
      const float a = __shfl(pn, (l & 56) | jj, 64);  // attn[i][jj]
      const int tv = blk * 8 + jj;
      bf16x8 v0 = *(const bf16x8*)(qk + tv * 1536 + (((vcc + d0) * 2)     ^ swz(tv)));
      bf16x8 v1 = *(const bf16x8*)(qk + tv * 1536 + (((vcc + d0 + 8) * 2) ^ swz(tv)));
#pragma unroll
      for (int c = 0; c < 8; ++c) { o[c] += a * bf2f(v0[c]); o[8 + c] += a * bf2f(v1[c]); }
    }
    float4* op = (float4*)(out + (tok0 + tq) * 256 + h * 128 + d0);
    op[0] = (float4){o[0],  o[1],  o[2],  o[3]};
    op[1] = (float4){o[4],  o[5],  o[6],  o[7]};
    op[2] = (float4){o[8],  o[9],  o[10], o[11]};
    op[3] = (float4){o[12], o[13], o[14], o[15]};
  }
}

extern "C" void kernel_launch(void* const* d_in, const int* in_sizes, int n_in,
                              void* d_out, int out_size, void* d_ws, size_t ws_size,
                              hipStream_t stream) {
  const float* x  = (const float*)d_in[0];
  const float* Wq = (const float*)d_in[1];
  const float* bq = (const float*)d_in[2];
  const float* Wk = (const float*)d_in[3];
  const float* bk = (const float*)d_in[4];
  const float* Wv = (const float*)d_in[5];
  const float* bv = (const float*)d_in[6];
  const float* P  = (const float*)d_in[7];
  float* out = (float*)d_out;

  short* WT   = (short*)d_ws;                          // 768*256 bf16 = 384 KB
  float* beff = (float*)((char*)d_ws + 768 * 256 * 2); // 768 fp32

  const int ntok = in_sizes[0] / 256;   // B*N = 65536
  prep_weights<<<768, 256, 0, stream>>>(Wq, bq, Wk, bk, Wv, bv, P, WT, beff);
  fused_qkv_attn<<<ntok / 32, 512, 0, stream>>>(x, WT, beff, out);
}